// Round 3
// baseline (394.741 us; speedup 1.0000x reference)
//
#include <hip/hip_runtime.h>
#include <hip/hip_fp16.h>

#define NV  778
#define NJT 16
#define NBP 135

// ---------------------------------------------------------------------------
// K0: batch-independent joint-regressor folding.
// SJ[k][j*3+c] = sum_v shapedirs[k][3v+c] * Jreg[v][j]   (480 dots)
// JT[j*3+c]    = sum_v v_template[3v+c]   * Jreg[v][j]   (48 dots)
// One wave per output dot.
// ---------------------------------------------------------------------------
__global__ void k0_fold_regressor(const float* __restrict__ v_template,
                                  const float* __restrict__ shapedirs,
                                  const float* __restrict__ Jreg,
                                  float* __restrict__ SJ,   // [10][48]
                                  float* __restrict__ JT)   // [48]
{
    int o = blockIdx.x;            // 0..527
    int lane = threadIdx.x;        // 0..63
    const float* src;
    int jc;
    if (o < 480) { int k = o / 48; jc = o % 48; src = shapedirs + (size_t)k * (NV*3); }
    else         { jc = o - 480;               src = v_template; }
    int j = jc / 3, c = jc % 3;
    float acc = 0.f;
    for (int v = lane; v < NV; v += 64)
        acc += src[3*v + c] * Jreg[v*NJT + j];
    for (int off = 32; off; off >>= 1) acc += __shfl_down(acc, off, 64);
    if (lane == 0) { if (o < 480) SJ[o] = acc; else JT[jc] = acc; }
}

// ---------------------------------------------------------------------------
// K1: per-batch-element small work. One 64-thread block per b.
// Outputs: pose_feature [B][135] (fp32), A [B][16][12] (fp32, top-3 rows)
// ---------------------------------------------------------------------------
__global__ void k1_perbatch(const float* __restrict__ beta,    // [B][10]
                            const float* __restrict__ theta,   // [B][48]
                            const float* __restrict__ hm,      // [45]
                            const float* __restrict__ hc,      // [45][45]
                            const float* __restrict__ SJ,
                            const float* __restrict__ JT,
                            float* __restrict__ pf_out,        // [B][135]
                            float* __restrict__ A_out)         // [B][192]
{
    int b = blockIdx.x;
    int t = threadIdx.x;           // 0..63
    __shared__ float s_theta[48];
    __shared__ float s_pose[48];
    __shared__ float s_beta[10];
    __shared__ float s_R[16][9];
    __shared__ float s_J[48];      // [j*3+c]
    __shared__ float s_res[16][12];

    if (t < 48) s_theta[t] = theta[(size_t)b*48 + t];
    if (t < 10) s_beta[t]  = beta[(size_t)b*10 + t];
    __syncthreads();

    if (t < 3) s_pose[t] = s_theta[t];
    if (t < 45) {
        float acc = hm[t];
        #pragma unroll 5
        for (int k = 0; k < 45; ++k) acc += s_theta[3+k] * hc[k*45 + t];
        s_pose[3+t] = acc;
    }
    if (t < 48) {
        float acc = JT[t];
        #pragma unroll
        for (int k = 0; k < 10; ++k) acc += s_beta[k] * SJ[k*48 + t];
        s_J[t] = acc;
    }
    __syncthreads();

    if (t < 16) {
        float rx = s_pose[3*t], ry = s_pose[3*t+1], rz = s_pose[3*t+2];
        float ex = rx + 1e-8f, ey = ry + 1e-8f, ez = rz + 1e-8f;
        float angle = sqrtf(ex*ex + ey*ey + ez*ez);
        float inv = 1.f / angle;
        float x = rx*inv, y = ry*inv, z = rz*inv;
        float s  = sinf(angle);
        float c1 = 1.f - cosf(angle);
        float R[9];
        R[0] = 1.f + c1*(-(z*z + y*y));
        R[1] = -s*z + c1*(x*y);
        R[2] =  s*y + c1*(x*z);
        R[3] =  s*z + c1*(x*y);
        R[4] = 1.f + c1*(-(x*x + z*z));
        R[5] = -s*x + c1*(y*z);
        R[6] = -s*y + c1*(x*z);
        R[7] =  s*x + c1*(y*z);
        R[8] = 1.f + c1*(-(x*x + y*y));
        #pragma unroll
        for (int i = 0; i < 9; ++i) s_R[t][i] = R[i];
        if (t >= 1) {
            float* dst = pf_out + (size_t)b*NBP + (t-1)*9;
            #pragma unroll
            for (int i = 0; i < 9; ++i) dst[i] = R[i] - ((i % 4 == 0) ? 1.f : 0.f);
        }
    }
    __syncthreads();

    if (t == 0) {
        const int parents[16] = {-1,0,1,2,0,4,5,0,7,8,0,10,11,0,13,14};
        #pragma unroll
        for (int p = 0; p < 3; ++p) {
            s_res[0][p*4+0] = s_R[0][p*3+0];
            s_res[0][p*4+1] = s_R[0][p*3+1];
            s_res[0][p*4+2] = s_R[0][p*3+2];
            s_res[0][p*4+3] = s_J[p];
        }
        #pragma unroll
        for (int i = 1; i < 16; ++i) {
            int pa = parents[i];
            float tx = s_J[i*3+0] - s_J[pa*3+0];
            float ty = s_J[i*3+1] - s_J[pa*3+1];
            float tz = s_J[i*3+2] - s_J[pa*3+2];
            #pragma unroll
            for (int p = 0; p < 3; ++p) {
                float pr0 = s_res[pa][p*4+0], pr1 = s_res[pa][p*4+1], pr2 = s_res[pa][p*4+2];
                #pragma unroll
                for (int q = 0; q < 3; ++q)
                    s_res[i][p*4+q] = pr0*s_R[i][0*3+q] + pr1*s_R[i][1*3+q] + pr2*s_R[i][2*3+q];
                s_res[i][p*4+3] = pr0*tx + pr1*ty + pr2*tz + s_res[pa][p*4+3];
            }
        }
        float* Ab = A_out + (size_t)b*192;
        #pragma unroll
        for (int i = 0; i < 16; ++i) {
            float jx = s_J[i*3], jy = s_J[i*3+1], jz = s_J[i*3+2];
            #pragma unroll
            for (int p = 0; p < 3; ++p) {
                float r0 = s_res[i][p*4+0], r1 = s_res[i][p*4+1], r2 = s_res[i][p*4+2];
                float ib = r0*jx + r1*jy + r2*jz;
                Ab[i*12+p*4+0] = r0;
                Ab[i*12+p*4+1] = r1;
                Ab[i*12+p*4+2] = r2;
                Ab[i*12+p*4+3] = s_res[i][p*4+3] - ib;
            }
        }
    }
}

// ---------------------------------------------------------------------------
// K2: per-vertex heavy kernel. Block = 128 threads, grid = (ceil(NV/128), B).
// ---------------------------------------------------------------------------
__launch_bounds__(128)
__global__ void k2_verts(const float* __restrict__ beta,
                         const float* __restrict__ v_template,
                         const float* __restrict__ shapedirs,   // [10][2334]
                         const float* __restrict__ posedirs,    // [135][2334]
                         const float* __restrict__ weights,     // [NV][16]
                         const float* __restrict__ pf_in,       // [B][135]
                         const float* __restrict__ A_in,        // [B][192]
                         _Float16* __restrict__ verts,          // [B][NV][3]
                         float* __restrict__ out)               // [B][21][3]
{
    int b = blockIdx.y;
    int t = threadIdx.x;
    int v = blockIdx.x * 128 + t;
    __shared__ float s_pf[NBP];
    __shared__ float s_A[192];
    __shared__ float s_beta[10];
    for (int i = t; i < NBP; i += 128) s_pf[i] = pf_in[(size_t)b*NBP + i];
    if (t < 10)  s_beta[t] = beta[(size_t)b*10 + t];
    for (int i = t; i < 192; i += 128) s_A[i] = A_in[(size_t)b*192 + i];
    __syncthreads();
    if (v >= NV) return;

    float vx = v_template[3*v+0];
    float vy = v_template[3*v+1];
    float vz = v_template[3*v+2];
    #pragma unroll
    for (int k = 0; k < 10; ++k) {
        const float* sd = shapedirs + (size_t)k*(NV*3) + 3*v;
        float bk = s_beta[k];
        vx += bk * sd[0];
        vy += bk * sd[1];
        vz += bk * sd[2];
    }
    #pragma unroll 5
    for (int p = 0; p < NBP; ++p) {
        const float* pd = posedirs + (size_t)p*(NV*3) + 3*v;
        float w = s_pf[p];
        vx += w * pd[0];
        vy += w * pd[1];
        vz += w * pd[2];
    }
    // skinning: M = sum_j weights[v][j] * A[j]
    float M[12];
    #pragma unroll
    for (int q = 0; q < 12; ++q) M[q] = 0.f;
    const float* wrow = weights + (size_t)v*16;
    #pragma unroll
    for (int j = 0; j < 16; ++j) {
        float wj = wrow[j];
        const float* Aj = s_A + j*12;
        #pragma unroll
        for (int q = 0; q < 12; ++q) M[q] += wj * Aj[q];
    }
    float o0 = M[0]*vx + M[1]*vy + M[2]*vz  + M[3];
    float o1 = M[4]*vx + M[5]*vy + M[6]*vz  + M[7];
    float o2 = M[8]*vx + M[9]*vy + M[10]*vz + M[11];

    size_t vo = ((size_t)b*NV + v)*3;
    verts[vo+0] = (_Float16)o0;
    verts[vo+1] = (_Float16)o1;
    verts[vo+2] = (_Float16)o2;

    int f = -1;
    if      (v == 734) f = 0;
    else if (v == 333) f = 1;
    else if (v == 443) f = 2;
    else if (v == 555) f = 3;
    else if (v == 678) f = 4;
    if (f >= 0) {
        size_t oo = ((size_t)b*21 + 16 + f)*3;
        out[oo+0] = o0;
        out[oo+1] = o1;
        out[oo+2] = o2;
    }
}

// ---------------------------------------------------------------------------
// K3: joints regression. One 256-thread block per b.
// joints[b][j][c] = sum_v verts[b][v][c] * Jreg[v][j]
// ---------------------------------------------------------------------------
__launch_bounds__(256)
__global__ void k3_joints(const _Float16* __restrict__ verts,
                          const float* __restrict__ Jreg,
                          float* __restrict__ out)
{
    int b = blockIdx.x;
    int t = threadIdx.x;
    float acc[48];
    #pragma unroll
    for (int i = 0; i < 48; ++i) acc[i] = 0.f;
    for (int v = t; v < NV; v += 256) {
        size_t vo = ((size_t)b*NV + v)*3;
        float vx = (float)verts[vo+0];
        float vy = (float)verts[vo+1];
        float vz = (float)verts[vo+2];
        const float* jr = Jreg + (size_t)v*16;
        #pragma unroll
        for (int j = 0; j < 16; ++j) {
            float w = jr[j];
            acc[j*3+0] += w*vx;
            acc[j*3+1] += w*vy;
            acc[j*3+2] += w*vz;
        }
    }
    __shared__ float s_red[4][48];
    int wave = t >> 6, lane = t & 63;
    #pragma unroll
    for (int i = 0; i < 48; ++i) {
        float a = acc[i];
        for (int off = 32; off; off >>= 1) a += __shfl_down(a, off, 64);
        if (lane == 0) s_red[wave][i] = a;
    }
    __syncthreads();
    if (t < 48) {
        float a = s_red[0][t] + s_red[1][t] + s_red[2][t] + s_red[3][t];
        out[(size_t)b*63 + t] = a;
    }
}

extern "C" void kernel_launch(void* const* d_in, const int* in_sizes, int n_in,
                              void* d_out, int out_size, void* d_ws, size_t ws_size,
                              hipStream_t stream) {
    // Reference dtypes are all float32 (jnp.float32) — cast accordingly.
    const float* beta       = (const float*)d_in[0];
    const float* theta      = (const float*)d_in[1];
    const float* v_template = (const float*)d_in[2];
    const float* shapedirs  = (const float*)d_in[3];
    const float* posedirs   = (const float*)d_in[4];
    const float* J_reg      = (const float*)d_in[5];
    const float* weights    = (const float*)d_in[6];
    const float* hands_mean = (const float*)d_in[7];
    const float* hands_comp = (const float*)d_in[8];
    float* out = (float*)d_out;

    const int B = in_sizes[0] / 10;

    // workspace layout
    char* ws = (char*)d_ws;
    float* SJ = (float*)ws;                       // 480 f32
    float* JT = SJ + 480;                         // 48 f32
    float* pf = (float*)(ws + 4096);              // B*135 f32
    float* A  = pf + (size_t)B * NBP;             // B*192 f32
    _Float16* verts = (_Float16*)(A + (size_t)B * 192);  // B*NV*3 fp16

    k0_fold_regressor<<<528, 64, 0, stream>>>(v_template, shapedirs, J_reg, SJ, JT);
    k1_perbatch<<<B, 64, 0, stream>>>(beta, theta, hands_mean, hands_comp, SJ, JT, pf, A);
    dim3 g2((NV + 127) / 128, B);
    k2_verts<<<g2, 128, 0, stream>>>(beta, v_template, shapedirs, posedirs, weights,
                                     pf, A, verts, out);
    k3_joints<<<B, 256, 0, stream>>>(verts, J_reg, out);
}

// Round 4
// 200.889 us; speedup vs baseline: 1.9650x; 1.9650x over previous
//
#include <hip/hip_runtime.h>

#define NV  778
#define NJT 16
#define NBP 135
#define G   8     // batch elements per k2 block
#define VT  128   // vertex tile per k2 block (= blockDim.x)

// ---------------------------------------------------------------------------
// K0: batch-independent joint-regressor folding.
// SJ[k][j*3+c] = sum_v shapedirs[k][3v+c] * Jreg[v][j]
// JT[j*3+c]    = sum_v v_template[3v+c]   * Jreg[v][j]
// ---------------------------------------------------------------------------
__global__ void k0_fold_regressor(const float* __restrict__ v_template,
                                  const float* __restrict__ shapedirs,
                                  const float* __restrict__ Jreg,
                                  float* __restrict__ SJ,   // [10][48]
                                  float* __restrict__ JT)   // [48]
{
    int o = blockIdx.x;            // 0..527
    int lane = threadIdx.x;        // 0..63
    const float* src;
    int jc;
    if (o < 480) { int k = o / 48; jc = o % 48; src = shapedirs + (size_t)k * (NV*3); }
    else         { jc = o - 480;               src = v_template; }
    int j = jc / 3, c = jc % 3;
    float acc = 0.f;
    for (int v = lane; v < NV; v += 64)
        acc += src[3*v + c] * Jreg[v*NJT + j];
    for (int off = 32; off; off >>= 1) acc += __shfl_down(acc, off, 64);
    if (lane == 0) { if (o < 480) SJ[o] = acc; else JT[jc] = acc; }
}

// ---------------------------------------------------------------------------
// K1: per-batch small work. One 64-thread block per b.
// pf_out is TRANSPOSED: pfT[p][B]  (so k2's 8 per-block values are contiguous)
// A_out [B][16][12]. Kinematic chain parallelized across 16 lanes: lane i
// walks 0 -> start -> ... -> i (chains are {3k+1,3k+2,3k+3}, depth<=4).
// ---------------------------------------------------------------------------
__global__ void k1_perbatch(const float* __restrict__ beta,    // [B][10]
                            const float* __restrict__ theta,   // [B][48]
                            const float* __restrict__ hm,      // [45]
                            const float* __restrict__ hc,      // [45][45]
                            const float* __restrict__ SJ,
                            const float* __restrict__ JT,
                            float* __restrict__ pfT,           // [135][B]
                            float* __restrict__ A_out,         // [B][192]
                            int Btot)
{
    int b = blockIdx.x;
    int t = threadIdx.x;           // 0..63
    __shared__ float s_theta[48];
    __shared__ float s_pose[48];
    __shared__ float s_beta[10];
    __shared__ float s_R[16][9];
    __shared__ float s_J[48];      // [j*3+c]

    if (t < 48) s_theta[t] = theta[(size_t)b*48 + t];
    if (t < 10) s_beta[t]  = beta[(size_t)b*10 + t];
    __syncthreads();

    if (t < 3) s_pose[t] = s_theta[t];
    if (t < 45) {
        float acc = hm[t];
        #pragma unroll 5
        for (int k = 0; k < 45; ++k) acc += s_theta[3+k] * hc[k*45 + t];
        s_pose[3+t] = acc;
    }
    if (t < 48) {
        float acc = JT[t];
        #pragma unroll
        for (int k = 0; k < 10; ++k) acc += s_beta[k] * SJ[k*48 + t];
        s_J[t] = acc;
    }
    __syncthreads();

    if (t < 16) {
        float rx = s_pose[3*t], ry = s_pose[3*t+1], rz = s_pose[3*t+2];
        float ex = rx + 1e-8f, ey = ry + 1e-8f, ez = rz + 1e-8f;
        float angle = sqrtf(ex*ex + ey*ey + ez*ez);
        float inv = 1.f / angle;
        float x = rx*inv, y = ry*inv, z = rz*inv;
        float s  = sinf(angle);
        float c1 = 1.f - cosf(angle);
        float R[9];
        R[0] = 1.f + c1*(-(z*z + y*y));
        R[1] = -s*z + c1*(x*y);
        R[2] =  s*y + c1*(x*z);
        R[3] =  s*z + c1*(x*y);
        R[4] = 1.f + c1*(-(x*x + z*z));
        R[5] = -s*x + c1*(y*z);
        R[6] = -s*y + c1*(x*z);
        R[7] =  s*x + c1*(y*z);
        R[8] = 1.f + c1*(-(x*x + y*y));
        #pragma unroll
        for (int i = 0; i < 9; ++i) s_R[t][i] = R[i];
        if (t >= 1) {
            // pose_feature transposed write: pfT[(t-1)*9+i][b]
            #pragma unroll
            for (int i = 0; i < 9; ++i)
                pfT[(size_t)((t-1)*9 + i) * Btot + b] = R[i] - ((i % 4 == 0) ? 1.f : 0.f);
        }
    }
    __syncthreads();

    if (t < 16) {
        // res = A_0 (3x4: [R0 | J0])
        float res[12];
        #pragma unroll
        for (int p = 0; p < 3; ++p) {
            res[p*4+0] = s_R[0][p*3+0];
            res[p*4+1] = s_R[0][p*3+1];
            res[p*4+2] = s_R[0][p*3+2];
            res[p*4+3] = s_J[p];
        }
        if (t >= 1) {
            int start = ((t-1)/3)*3 + 1;
            int d = t - start;          // 0..2
            for (int s = 0; s < 3; ++s) {
                if (s <= d) {
                    int a  = start + s;
                    int pa = (s == 0) ? 0 : (a - 1);
                    float ax = s_J[a*3+0] - s_J[pa*3+0];
                    float ay = s_J[a*3+1] - s_J[pa*3+1];
                    float az = s_J[a*3+2] - s_J[pa*3+2];
                    float nr[12];
                    #pragma unroll
                    for (int p = 0; p < 3; ++p) {
                        float r0 = res[p*4+0], r1 = res[p*4+1], r2 = res[p*4+2];
                        #pragma unroll
                        for (int q = 0; q < 3; ++q)
                            nr[p*4+q] = r0*s_R[a][q] + r1*s_R[a][3+q] + r2*s_R[a][6+q];
                        nr[p*4+3] = r0*ax + r1*ay + r2*az + res[p*4+3];
                    }
                    #pragma unroll
                    for (int q = 0; q < 12; ++q) res[q] = nr[q];
                }
            }
        }
        // subtract init_bone, write A
        float jx = s_J[t*3+0], jy = s_J[t*3+1], jz = s_J[t*3+2];
        float* Ab = A_out + (size_t)b*192 + t*12;
        #pragma unroll
        for (int p = 0; p < 3; ++p) {
            float r0 = res[p*4+0], r1 = res[p*4+1], r2 = res[p*4+2];
            float ib = r0*jx + r1*jy + r2*jz;
            Ab[p*4+0] = r0;
            Ab[p*4+1] = r1;
            Ab[p*4+2] = r2;
            Ab[p*4+3] = res[p*4+3] - ib;
        }
    }
}

// ---------------------------------------------------------------------------
// Kz: zero the output (joints are atomically accumulated).
// ---------------------------------------------------------------------------
__global__ void kz_zero(float* __restrict__ out, int n)
{
    int i = blockIdx.x * 256 + threadIdx.x;
    if (i < n) out[i] = 0.f;
}

// ---------------------------------------------------------------------------
// K2 fused: verts + skinning + joints partial-reduction.
// Block = VT(128) threads = 128 vertices; handles G(8) batch elements.
// Per-batch coefficients (beta/pfT/A) are read with block-uniform addresses
// (SMEM-promotable). Joints reduced per-block in LDS then atomicAdd.
// ---------------------------------------------------------------------------
__launch_bounds__(VT)
__global__ void k2_fused(const float* __restrict__ beta,       // [B][10]
                         const float* __restrict__ v_template, // [NV][3]
                         const float* __restrict__ shapedirs,  // [10][2334]
                         const float* __restrict__ posedirs,   // [135][2334]
                         const float* __restrict__ weights,    // [NV][16]
                         const float* __restrict__ Jreg,       // [NV][16]
                         const float* __restrict__ pfT,        // [135][B]
                         const float* __restrict__ A_in,       // [B][192]
                         float* __restrict__ out,              // [B][21][3]
                         int Btot)
{
    const int tid = threadIdx.x;
    const int v   = blockIdx.x * VT + tid;
    const int b0  = blockIdx.y * G;
    const bool valid = (v < NV);
    const int vc = valid ? v : 0;      // clamped index: uniform control flow

    __shared__ float s_jr[16][VT];     // Jreg rows, transposed (zero for invalid)
    __shared__ float s_verts[G][3][VT];

    // ---- stage Jreg row into LDS (transposed); zeros for invalid lanes ----
    {
        const float4* jp = (const float4*)(Jreg + (size_t)vc * 16);
        float4 j0 = jp[0], j1 = jp[1], j2 = jp[2], j3 = jp[3];
        float jf[16] = {j0.x,j0.y,j0.z,j0.w, j1.x,j1.y,j1.z,j1.w,
                        j2.x,j2.y,j2.z,j2.w, j3.x,j3.y,j3.z,j3.w};
        float m = valid ? 1.f : 0.f;
        #pragma unroll
        for (int j = 0; j < 16; ++j) s_jr[j][tid] = m * jf[j];
    }

    // ---- v_shaped/v_posed accumulators for G batches ----
    float tx = v_template[3*vc+0], ty = v_template[3*vc+1], tz = v_template[3*vc+2];
    float vx[G], vy[G], vz[G];
    #pragma unroll
    for (int g = 0; g < G; ++g) { vx[g]=tx; vy[g]=ty; vz[g]=tz; }

    // shapedirs (K=10), beta read block-uniform
    #pragma unroll
    for (int k = 0; k < 10; ++k) {
        const float* sd = shapedirs + (size_t)k*(NV*3) + 3*vc;
        float s0 = sd[0], s1 = sd[1], s2 = sd[2];
        const float* bp = beta + (size_t)b0*10 + k;
        #pragma unroll
        for (int g = 0; g < G; ++g) {
            float w = bp[g*10];
            vx[g] += w*s0; vy[g] += w*s1; vz[g] += w*s2;
        }
    }

    // posedirs (K=135), pfT read block-uniform (8 contiguous floats per p)
    const float* pwbase = pfT + b0;
    #pragma unroll 3
    for (int p = 0; p < NBP; ++p) {
        const float* pd = posedirs + (size_t)p*(NV*3) + 3*vc;
        float p0 = pd[0], p1 = pd[1], p2 = pd[2];
        const float* pw = pwbase + (size_t)p * Btot;
        #pragma unroll
        for (int g = 0; g < G; ++g) {
            float w = pw[g];
            vx[g] += w*p0; vy[g] += w*p1; vz[g] += w*p2;
        }
    }

    // ---- skinning: weights row per-lane; A block-uniform ----
    float wrow[16];
    {
        const float4* wp = (const float4*)(weights + (size_t)vc * 16);
        float4 w0 = wp[0], w1 = wp[1], w2 = wp[2], w3 = wp[3];
        wrow[0]=w0.x; wrow[1]=w0.y; wrow[2]=w0.z; wrow[3]=w0.w;
        wrow[4]=w1.x; wrow[5]=w1.y; wrow[6]=w1.z; wrow[7]=w1.w;
        wrow[8]=w2.x; wrow[9]=w2.y; wrow[10]=w2.z; wrow[11]=w2.w;
        wrow[12]=w3.x; wrow[13]=w3.y; wrow[14]=w3.z; wrow[15]=w3.w;
    }
    int f = -1;
    if      (v == 734) f = 0;
    else if (v == 333) f = 1;
    else if (v == 443) f = 2;
    else if (v == 555) f = 3;
    else if (v == 678) f = 4;

    #pragma unroll
    for (int g = 0; g < G; ++g) {
        const float* Ab = A_in + (size_t)(b0+g)*192;
        float M[12];
        #pragma unroll
        for (int q = 0; q < 12; ++q) M[q] = 0.f;
        #pragma unroll
        for (int j = 0; j < 16; ++j) {
            float wj = wrow[j];
            #pragma unroll
            for (int q = 0; q < 12; ++q) M[q] += wj * Ab[j*12+q];
        }
        float o0 = M[0]*vx[g] + M[1]*vy[g] + M[2]*vz[g]  + M[3];
        float o1 = M[4]*vx[g] + M[5]*vy[g] + M[6]*vz[g]  + M[7];
        float o2 = M[8]*vx[g] + M[9]*vy[g] + M[10]*vz[g] + M[11];
        s_verts[g][0][tid] = o0;
        s_verts[g][1][tid] = o1;
        s_verts[g][2][tid] = o2;
        if (f >= 0) {
            float* fo = out + (size_t)(b0+g)*63 + (16+f)*3;
            fo[0] = o0; fo[1] = o1; fo[2] = o2;
        }
    }
    __syncthreads();

    // ---- joints partial reduction: thread (j = tid&15, g = tid>>4) ----
    {
        int j = tid & 15, g = tid >> 4;
        float a0 = 0.f, a1 = 0.f, a2 = 0.f;
        #pragma unroll 4
        for (int l = 0; l < VT; l += 4) {
            float4 jr = *(const float4*)&s_jr[j][l];
            float4 q0 = *(const float4*)&s_verts[g][0][l];
            float4 q1 = *(const float4*)&s_verts[g][1][l];
            float4 q2 = *(const float4*)&s_verts[g][2][l];
            a0 += jr.x*q0.x + jr.y*q0.y + jr.z*q0.z + jr.w*q0.w;
            a1 += jr.x*q1.x + jr.y*q1.y + jr.z*q1.z + jr.w*q1.w;
            a2 += jr.x*q2.x + jr.y*q2.y + jr.z*q2.z + jr.w*q2.w;
        }
        float* ob = out + (size_t)(b0+g)*63 + j*3;
        atomicAdd(ob+0, a0);
        atomicAdd(ob+1, a1);
        atomicAdd(ob+2, a2);
    }
}

extern "C" void kernel_launch(void* const* d_in, const int* in_sizes, int n_in,
                              void* d_out, int out_size, void* d_ws, size_t ws_size,
                              hipStream_t stream) {
    const float* beta       = (const float*)d_in[0];
    const float* theta      = (const float*)d_in[1];
    const float* v_template = (const float*)d_in[2];
    const float* shapedirs  = (const float*)d_in[3];
    const float* posedirs   = (const float*)d_in[4];
    const float* J_reg      = (const float*)d_in[5];
    const float* weights    = (const float*)d_in[6];
    const float* hands_mean = (const float*)d_in[7];
    const float* hands_comp = (const float*)d_in[8];
    float* out = (float*)d_out;

    const int B = in_sizes[0] / 10;

    char* ws = (char*)d_ws;
    float* SJ  = (float*)ws;                       // 480 f32
    float* JT  = SJ + 480;                         // 48 f32
    float* pfT = (float*)(ws + 4096);              // [135][B] f32
    float* A   = pfT + (size_t)NBP * B;            // [B][192] f32

    k0_fold_regressor<<<528, 64, 0, stream>>>(v_template, shapedirs, J_reg, SJ, JT);
    k1_perbatch<<<B, 64, 0, stream>>>(beta, theta, hands_mean, hands_comp,
                                      SJ, JT, pfT, A, B);
    kz_zero<<<(B*63 + 255)/256, 256, 0, stream>>>(out, B*63);
    dim3 g2((NV + VT - 1)/VT, B/G);
    k2_fused<<<g2, VT, 0, stream>>>(beta, v_template, shapedirs, posedirs, weights,
                                    J_reg, pfT, A, out, B);
}

// Round 5
// 194.108 us; speedup vs baseline: 2.0336x; 1.0349x over previous
//
#include <hip/hip_runtime.h>

#define NV  778
#define NJT 16
#define NBP 135
#define G   8     // batch elements per k2 block
#define VT  128   // vertex tile per k2 block (= blockDim.x)
#define VTP (VT+4) // padded LDS row: 132 floats = 528B (16B-aligned, breaks bank alias)

// ---------------------------------------------------------------------------
// K0: batch-independent joint-regressor folding.
// ---------------------------------------------------------------------------
__global__ void k0_fold_regressor(const float* __restrict__ v_template,
                                  const float* __restrict__ shapedirs,
                                  const float* __restrict__ Jreg,
                                  float* __restrict__ SJ,   // [10][48]
                                  float* __restrict__ JT)   // [48]
{
    int o = blockIdx.x;            // 0..527
    int lane = threadIdx.x;        // 0..63
    const float* src;
    int jc;
    if (o < 480) { int k = o / 48; jc = o % 48; src = shapedirs + (size_t)k * (NV*3); }
    else         { jc = o - 480;               src = v_template; }
    int j = jc / 3, c = jc % 3;
    float acc = 0.f;
    for (int v = lane; v < NV; v += 64)
        acc += src[3*v + c] * Jreg[v*NJT + j];
    for (int off = 32; off; off >>= 1) acc += __shfl_down(acc, off, 64);
    if (lane == 0) { if (o < 480) SJ[o] = acc; else JT[jc] = acc; }
}

// ---------------------------------------------------------------------------
// K1 v2: 256-thread block = 4 waves = 4 batch elements (one wave per b).
// hc (8.1KB) + SJ/JT staged in LDS once per block -> kills the 45 serial
// L2-latency loads per wave that dominated R3's k1. Also zeroes the 48
// joint accumulators in `out` (kz kernel deleted).
// ---------------------------------------------------------------------------
__launch_bounds__(256)
__global__ void k1_perbatch(const float* __restrict__ beta,    // [B][10]
                            const float* __restrict__ theta,   // [B][48]
                            const float* __restrict__ hm,      // [45]
                            const float* __restrict__ hc,      // [45][45]
                            const float* __restrict__ SJ,
                            const float* __restrict__ JT,
                            float* __restrict__ pfT,           // [135][B]
                            float* __restrict__ A_out,         // [B][192]
                            float* __restrict__ out,           // [B][21][3]
                            int Btot)
{
    int w = threadIdx.x >> 6;      // wave 0..3
    int t = threadIdx.x & 63;      // lane
    int b = blockIdx.x * 4 + w;
    bool vb = (b < Btot);

    __shared__ float s_hc[45*45];
    __shared__ float s_SJ[480];
    __shared__ float s_JT[48];
    __shared__ float s_th[4][48];
    __shared__ float s_pose[4][48];
    __shared__ float s_J[4][48];
    __shared__ float s_R[4][16][9];

    for (int i = threadIdx.x; i < 45*45; i += 256) s_hc[i] = hc[i];
    for (int i = threadIdx.x; i < 480;   i += 256) s_SJ[i] = SJ[i];
    if (threadIdx.x < 48) s_JT[threadIdx.x] = JT[threadIdx.x];
    if (vb && t < 48) s_th[w][t] = theta[(size_t)b*48 + t];
    __syncthreads();

    if (vb) {
        if (t < 3) s_pose[w][t] = s_th[w][t];
        if (t < 45) {
            float acc = hm[t];
            #pragma unroll 9
            for (int k = 0; k < 45; ++k) acc += s_th[w][3+k] * s_hc[k*45 + t];
            s_pose[w][3+t] = acc;
        }
        if (t < 48) {
            float acc = s_JT[t];
            const float* bp = beta + (size_t)b*10;
            #pragma unroll
            for (int k = 0; k < 10; ++k) acc += bp[k] * s_SJ[k*48 + t];
            s_J[w][t] = acc;
        }
        // zero joint accumulators for k2's atomics
        if (t < 48) out[(size_t)b*63 + t] = 0.f;
    }
    __syncthreads();

    if (vb && t < 16) {
        float rx = s_pose[w][3*t], ry = s_pose[w][3*t+1], rz = s_pose[w][3*t+2];
        float ex = rx + 1e-8f, ey = ry + 1e-8f, ez = rz + 1e-8f;
        float angle = sqrtf(ex*ex + ey*ey + ez*ez);
        float inv = 1.f / angle;
        float x = rx*inv, y = ry*inv, z = rz*inv;
        float s  = sinf(angle);
        float c1 = 1.f - cosf(angle);
        float R[9];
        R[0] = 1.f + c1*(-(z*z + y*y));
        R[1] = -s*z + c1*(x*y);
        R[2] =  s*y + c1*(x*z);
        R[3] =  s*z + c1*(x*y);
        R[4] = 1.f + c1*(-(x*x + z*z));
        R[5] = -s*x + c1*(y*z);
        R[6] = -s*y + c1*(x*z);
        R[7] =  s*x + c1*(y*z);
        R[8] = 1.f + c1*(-(x*x + y*y));
        #pragma unroll
        for (int i = 0; i < 9; ++i) s_R[w][t][i] = R[i];
        if (t >= 1) {
            #pragma unroll
            for (int i = 0; i < 9; ++i)
                pfT[(size_t)((t-1)*9 + i) * Btot + b] = R[i] - ((i % 4 == 0) ? 1.f : 0.f);
        }
    }
    __syncthreads();

    if (vb && t < 16) {
        float res[12];
        #pragma unroll
        for (int p = 0; p < 3; ++p) {
            res[p*4+0] = s_R[w][0][p*3+0];
            res[p*4+1] = s_R[w][0][p*3+1];
            res[p*4+2] = s_R[w][0][p*3+2];
            res[p*4+3] = s_J[w][p];
        }
        if (t >= 1) {
            int start = ((t-1)/3)*3 + 1;
            int d = t - start;          // 0..2
            for (int s = 0; s < 3; ++s) {
                if (s <= d) {
                    int a  = start + s;
                    int pa = (s == 0) ? 0 : (a - 1);
                    float ax = s_J[w][a*3+0] - s_J[w][pa*3+0];
                    float ay = s_J[w][a*3+1] - s_J[w][pa*3+1];
                    float az = s_J[w][a*3+2] - s_J[w][pa*3+2];
                    float nr[12];
                    #pragma unroll
                    for (int p = 0; p < 3; ++p) {
                        float r0 = res[p*4+0], r1 = res[p*4+1], r2 = res[p*4+2];
                        #pragma unroll
                        for (int q = 0; q < 3; ++q)
                            nr[p*4+q] = r0*s_R[w][a][q] + r1*s_R[w][a][3+q] + r2*s_R[w][a][6+q];
                        nr[p*4+3] = r0*ax + r1*ay + r2*az + res[p*4+3];
                    }
                    #pragma unroll
                    for (int q = 0; q < 12; ++q) res[q] = nr[q];
                }
            }
        }
        float jx = s_J[w][t*3+0], jy = s_J[w][t*3+1], jz = s_J[w][t*3+2];
        float* Ab = A_out + (size_t)b*192 + t*12;
        #pragma unroll
        for (int p = 0; p < 3; ++p) {
            float r0 = res[p*4+0], r1 = res[p*4+1], r2 = res[p*4+2];
            float ib = r0*jx + r1*jy + r2*jz;
            Ab[p*4+0] = r0;
            Ab[p*4+1] = r1;
            Ab[p*4+2] = r2;
            Ab[p*4+3] = res[p*4+3] - ib;
        }
    }
}

// ---------------------------------------------------------------------------
// K2 fused: verts + skinning + joints partial-reduction.
// LDS rows padded to VTP=132 (bank-conflict-free reduction); joints
// reduction split into two 4-batch passes -> 14.8 KB LDS -> 10 blocks/CU.
// ---------------------------------------------------------------------------
__launch_bounds__(VT)
__global__ void k2_fused(const float* __restrict__ beta,       // [B][10]
                         const float* __restrict__ v_template, // [NV][3]
                         const float* __restrict__ shapedirs,  // [10][2334]
                         const float* __restrict__ posedirs,   // [135][2334]
                         const float* __restrict__ weights,    // [NV][16]
                         const float* __restrict__ Jreg,       // [NV][16]
                         const float* __restrict__ pfT,        // [135][B]
                         const float* __restrict__ A_in,       // [B][192]
                         float* __restrict__ out,              // [B][21][3]
                         int Btot)
{
    const int tid = threadIdx.x;
    const int v   = blockIdx.x * VT + tid;
    const int b0  = blockIdx.y * G;
    const bool valid = (v < NV);
    const int vc = valid ? v : 0;      // clamped: uniform control flow

    __shared__ float s_jr[16][VTP];    // 8448 B
    __shared__ float s_verts[4][3][VTP]; // 6336 B

    // ---- stage Jreg row into LDS (transposed); zeros for invalid lanes ----
    {
        const float4* jp = (const float4*)(Jreg + (size_t)vc * 16);
        float4 j0 = jp[0], j1 = jp[1], j2 = jp[2], j3 = jp[3];
        float jf[16] = {j0.x,j0.y,j0.z,j0.w, j1.x,j1.y,j1.z,j1.w,
                        j2.x,j2.y,j2.z,j2.w, j3.x,j3.y,j3.z,j3.w};
        float m = valid ? 1.f : 0.f;
        #pragma unroll
        for (int j = 0; j < 16; ++j) s_jr[j][tid] = m * jf[j];
    }

    // ---- v_shaped/v_posed accumulators for G batches ----
    float tx = v_template[3*vc+0], ty = v_template[3*vc+1], tz = v_template[3*vc+2];
    float vx[G], vy[G], vz[G];
    #pragma unroll
    for (int g = 0; g < G; ++g) { vx[g]=tx; vy[g]=ty; vz[g]=tz; }

    #pragma unroll
    for (int k = 0; k < 10; ++k) {
        const float* sd = shapedirs + (size_t)k*(NV*3) + 3*vc;
        float s0 = sd[0], s1 = sd[1], s2 = sd[2];
        const float* bp = beta + (size_t)b0*10 + k;
        #pragma unroll
        for (int g = 0; g < G; ++g) {
            float w = bp[g*10];
            vx[g] += w*s0; vy[g] += w*s1; vz[g] += w*s2;
        }
    }

    const float* pwbase = pfT + b0;
    #pragma unroll 5
    for (int p = 0; p < NBP; ++p) {
        const float* pd = posedirs + (size_t)p*(NV*3) + 3*vc;
        float p0 = pd[0], p1 = pd[1], p2 = pd[2];
        const float* pw = pwbase + (size_t)p * Btot;
        #pragma unroll
        for (int g = 0; g < G; ++g) {
            float w = pw[g];
            vx[g] += w*p0; vy[g] += w*p1; vz[g] += w*p2;
        }
    }

    // ---- per-vertex weights row ----
    float wrow[16];
    {
        const float4* wp = (const float4*)(weights + (size_t)vc * 16);
        float4 w0 = wp[0], w1 = wp[1], w2 = wp[2], w3 = wp[3];
        wrow[0]=w0.x; wrow[1]=w0.y; wrow[2]=w0.z; wrow[3]=w0.w;
        wrow[4]=w1.x; wrow[5]=w1.y; wrow[6]=w1.z; wrow[7]=w1.w;
        wrow[8]=w2.x; wrow[9]=w2.y; wrow[10]=w2.z; wrow[11]=w2.w;
        wrow[12]=w3.x; wrow[13]=w3.y; wrow[14]=w3.z; wrow[15]=w3.w;
    }
    int f = -1;
    if      (v == 734) f = 0;
    else if (v == 333) f = 1;
    else if (v == 443) f = 2;
    else if (v == 555) f = 3;
    else if (v == 678) f = 4;

    // ---- two passes: skinning (4 batches) -> LDS -> joints reduction ----
    const int rj = tid & 15, rg = (tid >> 4) & 3, rh = tid >> 6; // reduction role
    #pragma unroll
    for (int half = 0; half < 2; ++half) {
        __syncthreads();   // also orders s_jr writes before first read
        #pragma unroll
        for (int g4 = 0; g4 < 4; ++g4) {
            int g = half*4 + g4;
            const float* Ab = A_in + (size_t)(b0+g)*192;
            float M[12];
            #pragma unroll
            for (int q = 0; q < 12; ++q) M[q] = 0.f;
            #pragma unroll
            for (int j = 0; j < 16; ++j) {
                float wj = wrow[j];
                #pragma unroll
                for (int q = 0; q < 12; ++q) M[q] += wj * Ab[j*12+q];
            }
            float o0 = M[0]*vx[g] + M[1]*vy[g] + M[2]*vz[g]  + M[3];
            float o1 = M[4]*vx[g] + M[5]*vy[g] + M[6]*vz[g]  + M[7];
            float o2 = M[8]*vx[g] + M[9]*vy[g] + M[10]*vz[g] + M[11];
            s_verts[g4][0][tid] = o0;
            s_verts[g4][1][tid] = o1;
            s_verts[g4][2][tid] = o2;
            if (f >= 0) {
                float* fo = out + (size_t)(b0+g)*63 + (16+f)*3;
                fo[0] = o0; fo[1] = o1; fo[2] = o2;
            }
        }
        __syncthreads();
        float a0 = 0.f, a1 = 0.f, a2 = 0.f;
        int l0 = rh * 64;
        #pragma unroll 4
        for (int l = l0; l < l0 + 64; l += 4) {
            float4 jr = *(const float4*)&s_jr[rj][l];
            float4 q0 = *(const float4*)&s_verts[rg][0][l];
            float4 q1 = *(const float4*)&s_verts[rg][1][l];
            float4 q2 = *(const float4*)&s_verts[rg][2][l];
            a0 += jr.x*q0.x + jr.y*q0.y + jr.z*q0.z + jr.w*q0.w;
            a1 += jr.x*q1.x + jr.y*q1.y + jr.z*q1.z + jr.w*q1.w;
            a2 += jr.x*q2.x + jr.y*q2.y + jr.z*q2.z + jr.w*q2.w;
        }
        float* ob = out + (size_t)(b0 + half*4 + rg)*63 + rj*3;
        atomicAdd(ob+0, a0);
        atomicAdd(ob+1, a1);
        atomicAdd(ob+2, a2);
    }
}

extern "C" void kernel_launch(void* const* d_in, const int* in_sizes, int n_in,
                              void* d_out, int out_size, void* d_ws, size_t ws_size,
                              hipStream_t stream) {
    const float* beta       = (const float*)d_in[0];
    const float* theta      = (const float*)d_in[1];
    const float* v_template = (const float*)d_in[2];
    const float* shapedirs  = (const float*)d_in[3];
    const float* posedirs   = (const float*)d_in[4];
    const float* J_reg      = (const float*)d_in[5];
    const float* weights    = (const float*)d_in[6];
    const float* hands_mean = (const float*)d_in[7];
    const float* hands_comp = (const float*)d_in[8];
    float* out = (float*)d_out;

    const int B = in_sizes[0] / 10;

    char* ws = (char*)d_ws;
    float* SJ  = (float*)ws;                       // 480 f32
    float* JT  = SJ + 480;                         // 48 f32
    float* pfT = (float*)(ws + 4096);              // [135][B] f32
    float* A   = pfT + (size_t)NBP * B;            // [B][192] f32

    k0_fold_regressor<<<528, 64, 0, stream>>>(v_template, shapedirs, J_reg, SJ, JT);
    k1_perbatch<<<(B + 3)/4, 256, 0, stream>>>(beta, theta, hands_mean, hands_comp,
                                               SJ, JT, pfT, A, out, B);
    dim3 g2((NV + VT - 1)/VT, B/G);
    k2_fused<<<g2, VT, 0, stream>>>(beta, v_template, shapedirs, posedirs, weights,
                                    J_reg, pfT, A, out, B);
}

// Round 6
// 172.276 us; speedup vs baseline: 2.2913x; 1.1267x over previous
//
#include <hip/hip_runtime.h>

#define NV  778
#define NBP 135
#define NK  146   // coef length: 1 (template) + 10 (beta) + 135 (pose_feature)
#define GC  8     // batches per kC block

// Finger vertex ids
#define FV0 734
#define FV1 333
#define FV2 443
#define FV3 555
#define FV4 678

__device__ __forceinline__ const float* d_row(int k,
                                              const float* vt,
                                              const float* sd,
                                              const float* pd) {
    // D[k] row of the combined [146][2334] basis
    return (k == 0) ? vt : (k <= 10 ? sd + (size_t)(k-1)*(NV*3)
                                    : pd + (size_t)(k-11)*(NV*3));
}

// ---------------------------------------------------------------------------
// kA: batch-independent folds (64-thread blocks, role by blockIdx):
//   [0,528)     SJ[k][48] / JT[48]      (joint regressor vs shapedirs/template)
//   [528,784)   WJ[256]  = sum_v Jreg[v,J]*w[v,j]         (c = J*16+j)
//   [784,1562)  P[v][256] = Jreg[v,J]*w[v,j]
//   1562        Dfing[146][15], Wfing[5][16] gathers
//   (1562,1627) zero Gall (for kB's atomics)
// ---------------------------------------------------------------------------
__launch_bounds__(64)
__global__ void kA(const float* __restrict__ vt,
                   const float* __restrict__ sd,
                   const float* __restrict__ pd,
                   const float* __restrict__ jreg,
                   const float* __restrict__ wts,
                   float* __restrict__ SJ, float* __restrict__ JT,
                   float* __restrict__ WJ, float* __restrict__ P,
                   float* __restrict__ Dfing, float* __restrict__ Wfing,
                   float* __restrict__ Gall)
{
    const int o = blockIdx.x;
    const int t = threadIdx.x;
    const int fv[5] = {FV0, FV1, FV2, FV3, FV4};

    if (o < 528) {
        const float* src; int jc;
        if (o < 480) { int k = o / 48; jc = o % 48; src = sd + (size_t)k*(NV*3); }
        else         { jc = o - 480;               src = vt; }
        int j = jc / 3, c = jc % 3;
        float acc = 0.f;
        for (int v = t; v < NV; v += 64)
            acc += src[3*v + c] * jreg[v*16 + j];
        for (int off = 32; off; off >>= 1) acc += __shfl_down(acc, off, 64);
        if (t == 0) { if (o < 480) SJ[o] = acc; else JT[jc] = acc; }
    } else if (o < 784) {
        int c = o - 528, J = c >> 4, j = c & 15;
        float acc = 0.f;
        for (int v = t; v < NV; v += 64)
            acc += jreg[v*16 + J] * wts[v*16 + j];
        for (int off = 32; off; off >>= 1) acc += __shfl_down(acc, off, 64);
        if (t == 0) WJ[c] = acc;
    } else if (o < 1562) {
        int v = o - 784;
        #pragma unroll
        for (int m = 0; m < 4; ++m) {
            int c = t + 64*m;
            P[(size_t)v*256 + c] = jreg[v*16 + (c >> 4)] * wts[v*16 + (c & 15)];
        }
    } else if (o == 1562) {
        for (int e = t; e < NK*15; e += 64) {
            int k = e / 15, r = e % 15, f = r / 3, q = r % 3;
            Dfing[e] = d_row(k, vt, sd, pd)[3*fv[f] + q];
        }
        for (int e = t; e < 80; e += 64) {
            int f = e >> 4, j = e & 15;
            Wfing[e] = wts[fv[f]*16 + j];
        }
    } else {
        int z = o - 1563;  // 0..63
        for (int i = z*64 + t; i < NK*768; i += 64*64) Gall[i] = 0.f;
    }
}

// ---------------------------------------------------------------------------
// kB: Gall[k][q*256 + c] = sum_v D[k][3v+q] * P[v][c]
// grid = 146 k-rows x 2 v-halves, 256 threads (thread = c). atomicAdd merge.
// ---------------------------------------------------------------------------
__launch_bounds__(256)
__global__ void kB(const float* __restrict__ vt,
                   const float* __restrict__ sd,
                   const float* __restrict__ pd,
                   const float* __restrict__ P,
                   float* __restrict__ Gall)
{
    const int k = blockIdx.x >> 1;
    const int half = blockIdx.x & 1;
    const int t = threadIdx.x;
    const float* Drow = d_row(k, vt, sd, pd);
    const int v0 = half ? 389 : 0;
    const int v1 = half ? NV : 389;
    float a0 = 0.f, a1 = 0.f, a2 = 0.f;
    #pragma unroll 4
    for (int v = v0; v < v1; ++v) {
        float pv = P[(size_t)v*256 + t];
        a0 += Drow[3*v+0] * pv;
        a1 += Drow[3*v+1] * pv;
        a2 += Drow[3*v+2] * pv;
    }
    atomicAdd(&Gall[(size_t)k*768 +       t], a0);
    atomicAdd(&Gall[(size_t)k*768 + 256 + t], a1);
    atomicAdd(&Gall[(size_t)k*768 + 512 + t], a2);
}

// ---------------------------------------------------------------------------
// kC: everything per-batch. 256 threads, GC=8 batches/block.
// Phase 1: pose PCA + Rodrigues + joint chain -> coef[146], A[16][12] (LDS)
// Phase 2: S[g][768] = coef[g] @ Gall   (register acc, then LDS)
// Phase 3: joints = A (.) S + A[.,3] (.) WJ  -> out[0..15]
// Phase 4: 5 finger verts via Dfing/Wfing   -> out[16..20]
// ---------------------------------------------------------------------------
__launch_bounds__(256)
__global__ void kC(const float* __restrict__ beta,
                   const float* __restrict__ theta,
                   const float* __restrict__ hm,
                   const float* __restrict__ hc,
                   const float* __restrict__ SJ,
                   const float* __restrict__ JT,
                   const float* __restrict__ WJ,
                   const float* __restrict__ Gall,
                   const float* __restrict__ Dfing,
                   const float* __restrict__ Wfing,
                   float* __restrict__ out,
                   int Btot)
{
    const int tid = threadIdx.x;
    const int w = tid >> 6, t = tid & 63;
    const int b0 = blockIdx.x * GC;

    __shared__ float s_hc[2025];
    __shared__ float s_SJ[480];
    __shared__ float s_JT[48];
    __shared__ float s_WJ[256];
    __shared__ float s_th[GC][48];
    __shared__ float s_pose[GC][48];
    __shared__ float s_beta[GC][10];
    __shared__ float s_J[GC][48];
    __shared__ float s_R[GC][16][9];
    __shared__ float s_coef[GC][NK];
    __shared__ float s_A[GC][192];
    __shared__ float s_S[GC][768];
    __shared__ float s_vpf[GC][16];

    // ---- stage block-shared constants + per-batch inputs ----
    for (int i = tid; i < 2025; i += 256) s_hc[i] = hc[i];
    for (int i = tid; i < 480;  i += 256) s_SJ[i] = SJ[i];
    if (tid < 48) s_JT[tid] = JT[tid];
    if (tid < 256) s_WJ[tid] = WJ[tid];
    for (int i = tid; i < GC*48; i += 256) {
        int g = i / 48, tt = i % 48, b = b0 + g;
        s_th[g][tt] = (b < Btot) ? theta[(size_t)b*48 + tt] : 0.f;
    }
    for (int i = tid; i < GC*10; i += 256) {
        int g = i / 10, k = i % 10, b = b0 + g;
        s_beta[g][k] = (b < Btot) ? beta[(size_t)b*10 + k] : 0.f;
    }
    for (int i = tid; i < GC*NK; i += 256) ((float*)s_coef)[i] = 0.f;
    __syncthreads();

    // ---- phase 1: per-batch small work; wave w handles g = pp*4 + w ----
    #pragma unroll
    for (int pp = 0; pp < 2; ++pp) {
        int g = pp*4 + w;
        int b = b0 + g;
        if (b < Btot) {
            if (t < 3) s_pose[g][t] = s_th[g][t];
            if (t < 45) {
                float acc = hm[t];
                #pragma unroll 9
                for (int k = 0; k < 45; ++k) acc += s_th[g][3+k] * s_hc[k*45 + t];
                s_pose[g][3+t] = acc;
            }
            if (t < 48) {
                float acc = s_JT[t];
                #pragma unroll
                for (int k = 0; k < 10; ++k) acc += s_beta[g][k] * s_SJ[k*48 + t];
                s_J[g][t] = acc;
            }
            if (t < 10) s_coef[g][1+t] = s_beta[g][t];
            if (t == 10) s_coef[g][0] = 1.f;
            if (t < 16) {
                float rx = s_pose[g][3*t], ry = s_pose[g][3*t+1], rz = s_pose[g][3*t+2];
                float ex = rx + 1e-8f, ey = ry + 1e-8f, ez = rz + 1e-8f;
                float angle = sqrtf(ex*ex + ey*ey + ez*ez);
                float inv = 1.f / angle;
                float x = rx*inv, y = ry*inv, z = rz*inv;
                float s  = sinf(angle);
                float c1 = 1.f - cosf(angle);
                float R[9];
                R[0] = 1.f + c1*(-(z*z + y*y));
                R[1] = -s*z + c1*(x*y);
                R[2] =  s*y + c1*(x*z);
                R[3] =  s*z + c1*(x*y);
                R[4] = 1.f + c1*(-(x*x + z*z));
                R[5] = -s*x + c1*(y*z);
                R[6] = -s*y + c1*(x*z);
                R[7] =  s*x + c1*(y*z);
                R[8] = 1.f + c1*(-(x*x + y*y));
                #pragma unroll
                for (int i = 0; i < 9; ++i) s_R[g][t][i] = R[i];
                if (t >= 1) {
                    #pragma unroll
                    for (int i = 0; i < 9; ++i)
                        s_coef[g][11 + (t-1)*9 + i] = R[i] - ((i % 4 == 0) ? 1.f : 0.f);
                }
            }
            if (t < 16) {
                float res[12];
                #pragma unroll
                for (int p = 0; p < 3; ++p) {
                    res[p*4+0] = s_R[g][0][p*3+0];
                    res[p*4+1] = s_R[g][0][p*3+1];
                    res[p*4+2] = s_R[g][0][p*3+2];
                    res[p*4+3] = s_J[g][p];
                }
                if (t >= 1) {
                    int start = ((t-1)/3)*3 + 1;
                    int d = t - start;          // 0..2
                    for (int s = 0; s < 3; ++s) {
                        if (s <= d) {
                            int a  = start + s;
                            int pa = (s == 0) ? 0 : (a - 1);
                            float ax = s_J[g][a*3+0] - s_J[g][pa*3+0];
                            float ay = s_J[g][a*3+1] - s_J[g][pa*3+1];
                            float az = s_J[g][a*3+2] - s_J[g][pa*3+2];
                            float nr[12];
                            #pragma unroll
                            for (int p = 0; p < 3; ++p) {
                                float r0 = res[p*4+0], r1 = res[p*4+1], r2 = res[p*4+2];
                                #pragma unroll
                                for (int q = 0; q < 3; ++q)
                                    nr[p*4+q] = r0*s_R[g][a][q] + r1*s_R[g][a][3+q] + r2*s_R[g][a][6+q];
                                nr[p*4+3] = r0*ax + r1*ay + r2*az + res[p*4+3];
                            }
                            #pragma unroll
                            for (int q = 0; q < 12; ++q) res[q] = nr[q];
                        }
                    }
                }
                float jx = s_J[g][t*3+0], jy = s_J[g][t*3+1], jz = s_J[g][t*3+2];
                #pragma unroll
                for (int p = 0; p < 3; ++p) {
                    float r0 = res[p*4+0], r1 = res[p*4+1], r2 = res[p*4+2];
                    float ib = r0*jx + r1*jy + r2*jz;
                    s_A[g][t*12 + p*4+0] = r0;
                    s_A[g][t*12 + p*4+1] = r1;
                    s_A[g][t*12 + p*4+2] = r2;
                    s_A[g][t*12 + p*4+3] = res[p*4+3] - ib;
                }
            }
        }
    }
    __syncthreads();

    // ---- phase 2: S = coef @ Gall  (thread owns col c=tid, q=0..2, all g) ----
    {
        float acc[GC][3];
        #pragma unroll
        for (int g = 0; g < GC; ++g) { acc[g][0]=0.f; acc[g][1]=0.f; acc[g][2]=0.f; }
        #pragma unroll 2
        for (int k = 0; k < NK; ++k) {
            const float* Gr = Gall + (size_t)k*768;
            float g0 = Gr[tid], g1 = Gr[256 + tid], g2 = Gr[512 + tid];
            #pragma unroll
            for (int g = 0; g < GC; ++g) {
                float cf = s_coef[g][k];
                acc[g][0] += cf*g0; acc[g][1] += cf*g1; acc[g][2] += cf*g2;
            }
        }
        #pragma unroll
        for (int g = 0; g < GC; ++g) {
            s_S[g][tid]       = acc[g][0];
            s_S[g][256 + tid] = acc[g][1];
            s_S[g][512 + tid] = acc[g][2];
        }
    }
    __syncthreads();

    // ---- phase 3: joints[b,J,p] ----
    for (int o = tid; o < GC*48; o += 256) {
        int g = o / 48, rem = o % 48, J = rem / 3, p = rem % 3;
        int b = b0 + g;
        if (b < Btot) {
            const float* Ag = s_A[g];
            float val = 0.f;
            #pragma unroll
            for (int j = 0; j < 16; ++j) {
                float a0 = Ag[j*12 + p*4 + 0];
                float a1 = Ag[j*12 + p*4 + 1];
                float a2 = Ag[j*12 + p*4 + 2];
                float a3 = Ag[j*12 + p*4 + 3];
                val += a0 * s_S[g][        J*16 + j]
                     + a1 * s_S[g][256 +   J*16 + j]
                     + a2 * s_S[g][512 +   J*16 + j]
                     + a3 * s_WJ[J*16 + j];
            }
            out[(size_t)b*63 + J*3 + p] = val;
        }
    }

    // ---- phase 4: finger vertices ----
    if (tid < GC*15) {
        int g = tid / 15, r = tid % 15;
        float acc = 0.f;
        #pragma unroll 2
        for (int k = 0; k < NK; ++k) acc += s_coef[g][k] * Dfing[k*15 + r];
        s_vpf[g][r] = acc;
    }
    __syncthreads();
    if (tid < GC*15) {
        int g = tid / 15, r = tid % 15, f = r / 3, p = r % 3;
        int b = b0 + g;
        if (b < Btot) {
            const float* Ag = s_A[g];
            float vx = s_vpf[g][f*3+0], vy = s_vpf[g][f*3+1], vz = s_vpf[g][f*3+2];
            float val = 0.f;
            #pragma unroll
            for (int j = 0; j < 16; ++j) {
                float wj = Wfing[f*16 + j];
                val += wj * (Ag[j*12 + p*4 + 0]*vx +
                             Ag[j*12 + p*4 + 1]*vy +
                             Ag[j*12 + p*4 + 2]*vz +
                             Ag[j*12 + p*4 + 3]);
            }
            out[(size_t)b*63 + (16+f)*3 + p] = val;
        }
    }
}

extern "C" void kernel_launch(void* const* d_in, const int* in_sizes, int n_in,
                              void* d_out, int out_size, void* d_ws, size_t ws_size,
                              hipStream_t stream) {
    const float* beta       = (const float*)d_in[0];
    const float* theta      = (const float*)d_in[1];
    const float* v_template = (const float*)d_in[2];
    const float* shapedirs  = (const float*)d_in[3];
    const float* posedirs   = (const float*)d_in[4];
    const float* J_reg      = (const float*)d_in[5];
    const float* weights    = (const float*)d_in[6];
    const float* hands_mean = (const float*)d_in[7];
    const float* hands_comp = (const float*)d_in[8];
    float* out = (float*)d_out;

    const int B = in_sizes[0] / 10;

    // workspace layout (floats)
    float* W = (float*)d_ws;
    float* SJ    = W;                    // 480
    float* JT    = W + 480;              // 48
    float* WJ    = W + 528;              // 256
    float* Dfing = W + 784;              // 146*15 = 2190
    float* Wfing = W + 2974;             // 80
    float* P     = W + 3072;             // 778*256 = 199168
    float* Gall  = W + 202240;           // 146*768 = 112128

    kA<<<1627, 64, 0, stream>>>(v_template, shapedirs, posedirs, J_reg, weights,
                                SJ, JT, WJ, P, Dfing, Wfing, Gall);
    kB<<<292, 256, 0, stream>>>(v_template, shapedirs, posedirs, P, Gall);
    kC<<<(B + GC - 1)/GC, 256, 0, stream>>>(beta, theta, hands_mean, hands_comp,
                                            SJ, JT, WJ, Gall, Dfing, Wfing, out, B);
}